// Round 8
// baseline (201.934 us; speedup 1.0000x reference)
//
#include <hip/hip_runtime.h>
#include <hip/hip_bf16.h>
#include <cstdint>
#include <cstddef>

#define C_N 100000
#define B_N 512
#define D_N 512

#define COS_M_F   0.87758256189037276f
#define SIN_M_F   0.47942553860420301f
#define THRESH_F  (-0.87758256189037276f)
#define MM_F      0.23971276930210150f
#define S_F       64.0f

typedef __attribute__((ext_vector_type(8))) short short8;
typedef __attribute__((ext_vector_type(4))) float f32x4;

__device__ __forceinline__ unsigned short f2bf(float f) {
  unsigned u = __float_as_uint(f);
  u = u + 0x7fffu + ((u >> 16) & 1u);
  return (unsigned short)(u >> 16);
}

__device__ __forceinline__ float wave_sum(float v) {
#pragma unroll
  for (int o = 32; o > 0; o >>= 1) v += __shfl_down(v, o, 64);
  return v;
}

__device__ __forceinline__ void lds_load16(const void* g, void* l) {
  __builtin_amdgcn_global_load_lds(
      (const __attribute__((address_space(1))) unsigned int*)g,
      (__attribute__((address_space(3))) unsigned int*)l, 16, 0, 0);
}

// ---------------- kernel N1v2 (R3-verified): col-norm + transpose -> Knt -----
__launch_bounds__(512)
__global__ void knorm2_k(const float* __restrict__ Kp, float* __restrict__ cninv,
                         unsigned short* __restrict__ Knt) {
  __shared__ __align__(16) unsigned short Tl[64 * 512];
  __shared__ float ssum[32][64];
  __shared__ float cns[64];

  const int t = threadIdx.x;
  const int j0 = blockIdx.x * 64;
  const int jq = t & 15;
  const int dr = t >> 4;
  const int jcol = min((j0 >> 2) + jq, (C_N >> 2) - 1);
  const float4* __restrict__ Kv = (const float4*)Kp;

  float4 v[16];
#pragma unroll
  for (int i = 0; i < 16; ++i)
    v[i] = Kv[(size_t)(dr * 16 + i) * (C_N / 4) + jcol];

  float s0 = 0.f, s1 = 0.f, s2 = 0.f, s3 = 0.f;
#pragma unroll
  for (int i = 0; i < 16; ++i) {
    s0 = fmaf(v[i].x, v[i].x, s0);
    s1 = fmaf(v[i].y, v[i].y, s1);
    s2 = fmaf(v[i].z, v[i].z, s2);
    s3 = fmaf(v[i].w, v[i].w, s3);
  }
  ssum[dr][jq * 4 + 0] = s0;
  ssum[dr][jq * 4 + 1] = s1;
  ssum[dr][jq * 4 + 2] = s2;
  ssum[dr][jq * 4 + 3] = s3;
  __syncthreads();
  if (t < 64) {
    float s = 0.f;
#pragma unroll
    for (int d = 0; d < 32; ++d) s += ssum[d][t];
    float r = rsqrtf(fmaxf(s, 1e-30f));
    cns[t] = r;
    if (j0 + t < C_N) cninv[j0 + t] = r;
  }
  __syncthreads();

  const float r0 = cns[jq * 4 + 0];
  const float r1 = cns[jq * 4 + 1];
  const float r2 = cns[jq * 4 + 2];
  const float r3 = cns[jq * 4 + 3];
#pragma unroll
  for (int g = 0; g < 4; ++g) {
    const int ch = dr * 2 + (g >> 1);
    const int sub = (g & 1) * 8;
#pragma unroll
    for (int c = 0; c < 4; ++c) {
      const int j = jq * 4 + c;
      const float rc = (c == 0) ? r0 : (c == 1) ? r1 : (c == 2) ? r2 : r3;
      unsigned lo, hi;
      lo = (unsigned)f2bf(v[g * 4 + 0][c] * rc) | ((unsigned)f2bf(v[g * 4 + 1][c] * rc) << 16);
      hi = (unsigned)f2bf(v[g * 4 + 2][c] * rc) | ((unsigned)f2bf(v[g * 4 + 3][c] * rc) << 16);
      const int phys = ch ^ (j & 7);
      *(uint2*)((char*)Tl + j * 1024 + phys * 16 + sub) = make_uint2(lo, hi);
    }
  }
  __syncthreads();

  const int jr = t >> 3;
  const int dc = t & 7;
  const int jg = j0 + jr;
  if (jg < C_N) {
#pragma unroll
    for (int s = 0; s < 8; ++s) {
      const int phys = (s * 8) + (dc ^ (jr & 7));
      uint4 val = *(const uint4*)((const char*)Tl + jr * 1024 + phys * 16);
      *(uint4*)(&Knt[(size_t)jg * D_N + s * 64 + dc * 8]) = val;
    }
  }
}

// ---------------- kernel 2: embedding row normalize -> bf16 ------------------
__global__ void embnorm_k(const float* __restrict__ emb, unsigned short* __restrict__ embn,
                          float* __restrict__ rinv) {
  int row = blockIdx.x;
  int t = threadIdx.x;
  float4 v = ((const float4*)(emb + (size_t)row * D_N))[t];
  float ss = v.x * v.x + v.y * v.y + v.z * v.z + v.w * v.w;
  ss = wave_sum(ss);
  __shared__ float red[2];
  if ((t & 63) == 0) red[t >> 6] = ss;
  __syncthreads();
  float tot = red[0] + red[1];
  float ri = rsqrtf(tot);
  if (t == 0) rinv[row] = ri;
  ushort4 o;
  o.x = f2bf(v.x * ri); o.y = f2bf(v.y * ri); o.z = f2bf(v.z * ri); o.w = f2bf(v.w * ri);
  ((ushort4*)(embn + (size_t)row * D_N))[t] = o;
}

// ---------------- kernel 3: target logit (computes own label-col norm) -------
__global__ void target2_k(const float* __restrict__ emb, const float* __restrict__ Kp,
                          const float* __restrict__ rinv, const int* __restrict__ labels,
                          float* __restrict__ target, float* __restrict__ ctm,
                          float* __restrict__ ft) {
  int row = blockIdx.x;
  int t = threadIdx.x;
  int lab = labels[row];
  float p = 0.f, ss = 0.f;
  for (int d = t; d < D_N; d += 256) {
    float kv = Kp[(size_t)d * C_N + lab];
    p = fmaf(emb[(size_t)row * D_N + d], kv, p);
    ss = fmaf(kv, kv, ss);
  }
  p = wave_sum(p);
  ss = wave_sum(ss);
  __shared__ float redp[4], reds[4];
  if ((t & 63) == 0) { redp[t >> 6] = p; reds[t >> 6] = ss; }
  __syncthreads();
  if (t == 0) {
    float dot = redp[0] + redp[1] + redp[2] + redp[3];
    float sums = reds[0] + reds[1] + reds[2] + reds[3];
    float tg = dot * rinv[row] * rsqrtf(fmaxf(sums, 1e-30f));
    tg = fminf(fmaxf(tg, -1.f), 1.f);
    float st = sqrtf(fmaxf(1.f - tg * tg, 0.f));
    float cm = tg * COS_M_F - st * SIN_M_F;
    float f = (tg > THRESH_F) ? cm : (tg - MM_F);
    target[row] = tg;
    ctm[row] = cm;
    ft[row] = f;
  }
}

// ---------------- kernel 4: new_t reduction ----------------------------------
__global__ void newt_k(const float* __restrict__ target, const float* __restrict__ t_in,
                       float* __restrict__ newt) {
  int t = threadIdx.x;
  float v = target[t];
  v = wave_sum(v);
  __shared__ float red[8];
  if ((t & 63) == 0) red[t >> 6] = v;
  __syncthreads();
  if (t == 0) {
    float s = 0.f;
#pragma unroll
    for (int i = 0; i < 8; ++i) s += red[i];
    *newt = 0.01f * (s / (float)B_N) + 0.99f * t_in[0];
  }
}

// ---------------- kernel G9: gemm8 + counted-vmcnt loop + XCD swizzle --------
// Identical geometry/swizzles/epilogue to gemm8 (verified). Loop changed to
// T3/T4: raw s_barrier, per-wave counted vmcnt (never 0 mid-loop), depth-2
// prefetch over the 2 LDS buffers. Closing barrier drains lgkm only.
__launch_bounds__(1024, 4)
__global__ void gemm9_k(const unsigned short* __restrict__ Knt,
                        const unsigned short* __restrict__ embn,
                        const int* __restrict__ labels,
                        const float* __restrict__ ctm, const float* __restrict__ ft,
                        const float* __restrict__ newt_p, float* __restrict__ out) {
  __shared__ __align__(16) char lds[81920];
  unsigned short* Al = (unsigned short*)lds;            // 2 x 32768 B
  unsigned short* Bb = (unsigned short*)(lds + 65536);  // 2 x 8192 B

  const int t = threadIdx.x;
  const int l = t & 63, w = t >> 6;

  // bijective XCD swizzle of j-blocks (nwg=782 = 8*97+6; m204 formula)
  const int nwg = gridDim.x;
  const int q = nwg >> 3, r = nwg & 7;
  const int xcd = blockIdx.x & 7, seq = blockIdx.x >> 3;
  const int wg = (xcd < r ? xcd * (q + 1) : r * (q + 1) + (xcd - r) * q) + seq;
  const int j0 = wg * 128;

  const int sidx = (l & 7) ^ (l >> 3);
  const int r0 = ((l >> 3) << 1) | (sidx >> 2);
  const int kc8 = (sidx & 3) * 8;

  const unsigned short* asrc = embn + (size_t)(w * 32 + r0) * D_N + kc8;
  const unsigned short* bsrc = Knt + (size_t)(j0 + (w & 7) * 16 + r0) * D_N + kc8;

#define STAGE9(it, buf)                                                        \
  do {                                                                         \
    const int k0_ = (it) * 32;                                                 \
    lds_load16(asrc + k0_, Al + (buf) * 16384 + w * 1024);                     \
    lds_load16(asrc + 16 * D_N + k0_, Al + (buf) * 16384 + w * 1024 + 512);    \
    if (w < 8) lds_load16(bsrc + k0_, Bb + (buf) * 4096 + w * 512);            \
  } while (0)

  // prologue: two tiles in flight
  STAGE9(0, 0);
  STAGE9(1, 1);

  const int wr = w >> 2, wc = w & 3;
  const int lq = l >> 4, lr = l & 15;
  const int s16 = ((((lr & 1) << 2) | lq) ^ (lr >> 1)) << 4;
  const int rh = lr >> 1;

  f32x4 acc[8][2];
#pragma unroll
  for (int mb = 0; mb < 8; ++mb) {
    acc[mb][0] = 0;
    acc[mb][1] = 0;
  }

#pragma unroll
  for (int it = 0; it < 16; ++it) {
    const int cur = it & 1;
    if (it >= 1 && it < 15) STAGE9(it + 1, cur ^ 1);
    // opening: wait for stage(it) only (keep stage(it+1) in flight), barrier
    if (it == 15) {
      asm volatile("s_waitcnt vmcnt(0)" ::: "memory");
    } else if (w < 8) {
      asm volatile("s_waitcnt vmcnt(3)" ::: "memory");
    } else {
      asm volatile("s_waitcnt vmcnt(2)" ::: "memory");
    }
    __builtin_amdgcn_sched_barrier(0);
    __builtin_amdgcn_s_barrier();
    __builtin_amdgcn_sched_barrier(0);

    const char* Ab = (const char*)(Al + cur * 16384);
    const char* Bt = (const char*)(Bb + cur * 4096);
    short8 b0 = *(const short8*)(Bt + ((wc * 16 + 0 + rh) << 7) + s16);
    short8 b1 = *(const short8*)(Bt + ((wc * 16 + 8 + rh) << 7) + s16);
#pragma unroll
    for (int mb = 0; mb < 8; ++mb) {
      short8 a = *(const short8*)(Ab + ((wr * 64 + mb * 8 + rh) << 7) + s16);
      acc[mb][0] = __builtin_amdgcn_mfma_f32_16x16x32_bf16(a, b0, acc[mb][0], 0, 0, 0);
      acc[mb][1] = __builtin_amdgcn_mfma_f32_16x16x32_bf16(a, b1, acc[mb][1], 0, 0, 0);
    }
    // closing: drain LDS reads only (NOT vmcnt), barrier
    asm volatile("s_waitcnt lgkmcnt(0)" ::: "memory");
    __builtin_amdgcn_sched_barrier(0);
    __builtin_amdgcn_s_barrier();
    __builtin_amdgcn_sched_barrier(0);
  }
#undef STAGE9

  // ---- epilogue: 4 passes, acc -> LDS (reuse A region) -> contiguous stores -
  const float newt = *newt_p;
  float* Tl = (float*)lds;
  const int row_l = t >> 3;
  const int sgl = t & 7;
  const int rx = row_l & 7;

#pragma unroll
  for (int pp = 0; pp < 4; ++pp) {
    if (wr == pp) {
#pragma unroll
      for (int mb = 0; mb < 8; ++mb) {
#pragma unroll
        for (int nb = 0; nb < 2; ++nb) {
          const int seg = nb * 4 + (lr >> 2);
          const int e = lr & 3;
#pragma unroll
          for (int rr = 0; rr < 4; ++rr) {
            const int rl = mb * 16 + lq * 4 + rr;
            const int ps = seg ^ (rl & 7);
            Tl[rl * 128 + wc * 32 + ps * 4 + e] = acc[mb][nb][rr];
          }
        }
      }
    }
    __syncthreads();
    const int grow = pp * 128 + row_l;
    const int lab = labels[grow];
    const float cm = ctm[grow];
    const float f = ft[grow];
#pragma unroll
    for (int k = 0; k < 4; ++k) {
      const int jb = j0 + k * 32 + sgl * 4;
      if (jb < C_N) {
        f32x4 vv = *(const f32x4*)&Tl[row_l * 128 + k * 32 + (sgl ^ rx) * 4];
#pragma unroll
        for (int e = 0; e < 4; ++e) {
          float c = fminf(fmaxf(vv[e], -1.f), 1.f);
          float o = (c > cm) ? c * (newt + c) : c;
          o = (jb + e == lab) ? f : o;
          vv[e] = o * S_F;
        }
        *(f32x4*)&out[(size_t)grow * C_N + jb] = vv;
      }
    }
    __syncthreads();
  }
}

// ---------------- launch -----------------------------------------------------
extern "C" void kernel_launch(void* const* d_in, const int* in_sizes, int n_in,
                              void* d_out, int out_size, void* d_ws, size_t ws_size,
                              hipStream_t stream) {
  (void)in_sizes; (void)n_in; (void)out_size; (void)ws_size;
  const float* emb = (const float*)d_in[0];
  const int* labels = (const int*)d_in[1];
  const float* Kp = (const float*)d_in[2];
  const float* t_in = (const float*)d_in[3];
  float* out = (float*)d_out;

  char* wsp = (char*)d_ws;
  const size_t KNT_BYTES = (size_t)100096 * D_N * 2;
  unsigned short* Knt = (unsigned short*)(wsp + 0);
  unsigned short* embn = (unsigned short*)(wsp + KNT_BYTES);
  float* cninv  = (float*)(wsp + KNT_BYTES + 524288);
  float* target = (float*)(wsp + KNT_BYTES + 524288 + 400000);
  float* ctm    = (float*)(wsp + KNT_BYTES + 524288 + 400000 + 2048);
  float* ft     = (float*)(wsp + KNT_BYTES + 524288 + 400000 + 2 * 2048);
  float* rinv   = (float*)(wsp + KNT_BYTES + 524288 + 400000 + 3 * 2048);
  float* newt   = (float*)(wsp + KNT_BYTES + 524288 + 400000 + 4 * 2048);

  knorm2_k<<<(C_N + 63) / 64, 512, 0, stream>>>(Kp, cninv, Knt);
  embnorm_k<<<B_N, 128, 0, stream>>>(emb, embn, rinv);
  target2_k<<<B_N, 256, 0, stream>>>(emb, Kp, rinv, labels, target, ctm, ft);
  newt_k<<<1, 512, 0, stream>>>(target, t_in, newt);
  gemm9_k<<<(C_N + 127) / 128, 1024, 0, stream>>>(Knt, embn, labels, ctm, ft, newt, out);
}

// Round 9
// 194.167 us; speedup vs baseline: 1.0400x; 1.0400x over previous
//
#include <hip/hip_runtime.h>
#include <hip/hip_bf16.h>
#include <cstdint>
#include <cstddef>

#define C_N 100000
#define B_N 512
#define D_N 512

#define COS_M_F   0.87758256189037276f
#define SIN_M_F   0.47942553860420301f
#define THRESH_F  (-0.87758256189037276f)
#define MM_F      0.23971276930210150f
#define S_F       64.0f

typedef __attribute__((ext_vector_type(8))) short short8;
typedef __attribute__((ext_vector_type(4))) float f32x4;

__device__ __forceinline__ unsigned short f2bf(float f) {
  unsigned u = __float_as_uint(f);
  u = u + 0x7fffu + ((u >> 16) & 1u);
  return (unsigned short)(u >> 16);
}

__device__ __forceinline__ float wave_sum(float v) {
#pragma unroll
  for (int o = 32; o > 0; o >>= 1) v += __shfl_down(v, o, 64);
  return v;
}

__device__ __forceinline__ void lds_load16(const void* g, void* l) {
  __builtin_amdgcn_global_load_lds(
      (const __attribute__((address_space(1))) unsigned int*)g,
      (__attribute__((address_space(3))) unsigned int*)l, 16, 0, 0);
}

// ---------------- kernel N1v2 (R3-verified): col-norm + transpose -> Knt -----
__launch_bounds__(512)
__global__ void knorm2_k(const float* __restrict__ Kp, float* __restrict__ cninv,
                         unsigned short* __restrict__ Knt) {
  __shared__ __align__(16) unsigned short Tl[64 * 512];
  __shared__ float ssum[32][64];
  __shared__ float cns[64];

  const int t = threadIdx.x;
  const int j0 = blockIdx.x * 64;
  const int jq = t & 15;
  const int dr = t >> 4;
  const int jcol = min((j0 >> 2) + jq, (C_N >> 2) - 1);
  const float4* __restrict__ Kv = (const float4*)Kp;

  float4 v[16];
#pragma unroll
  for (int i = 0; i < 16; ++i)
    v[i] = Kv[(size_t)(dr * 16 + i) * (C_N / 4) + jcol];

  float s0 = 0.f, s1 = 0.f, s2 = 0.f, s3 = 0.f;
#pragma unroll
  for (int i = 0; i < 16; ++i) {
    s0 = fmaf(v[i].x, v[i].x, s0);
    s1 = fmaf(v[i].y, v[i].y, s1);
    s2 = fmaf(v[i].z, v[i].z, s2);
    s3 = fmaf(v[i].w, v[i].w, s3);
  }
  ssum[dr][jq * 4 + 0] = s0;
  ssum[dr][jq * 4 + 1] = s1;
  ssum[dr][jq * 4 + 2] = s2;
  ssum[dr][jq * 4 + 3] = s3;
  __syncthreads();
  if (t < 64) {
    float s = 0.f;
#pragma unroll
    for (int d = 0; d < 32; ++d) s += ssum[d][t];
    float r = rsqrtf(fmaxf(s, 1e-30f));
    cns[t] = r;
    if (j0 + t < C_N) cninv[j0 + t] = r;
  }
  __syncthreads();

  const float r0 = cns[jq * 4 + 0];
  const float r1 = cns[jq * 4 + 1];
  const float r2 = cns[jq * 4 + 2];
  const float r3 = cns[jq * 4 + 3];
#pragma unroll
  for (int g = 0; g < 4; ++g) {
    const int ch = dr * 2 + (g >> 1);
    const int sub = (g & 1) * 8;
#pragma unroll
    for (int c = 0; c < 4; ++c) {
      const int j = jq * 4 + c;
      const float rc = (c == 0) ? r0 : (c == 1) ? r1 : (c == 2) ? r2 : r3;
      unsigned lo, hi;
      lo = (unsigned)f2bf(v[g * 4 + 0][c] * rc) | ((unsigned)f2bf(v[g * 4 + 1][c] * rc) << 16);
      hi = (unsigned)f2bf(v[g * 4 + 2][c] * rc) | ((unsigned)f2bf(v[g * 4 + 3][c] * rc) << 16);
      const int phys = ch ^ (j & 7);
      *(uint2*)((char*)Tl + j * 1024 + phys * 16 + sub) = make_uint2(lo, hi);
    }
  }
  __syncthreads();

  const int jr = t >> 3;
  const int dc = t & 7;
  const int jg = j0 + jr;
  if (jg < C_N) {
#pragma unroll
    for (int s = 0; s < 8; ++s) {
      const int phys = (s * 8) + (dc ^ (jr & 7));
      uint4 val = *(const uint4*)((const char*)Tl + jr * 1024 + phys * 16);
      *(uint4*)(&Knt[(size_t)jg * D_N + s * 64 + dc * 8]) = val;
    }
  }
}

// ---------------- kernel 2: embedding row normalize -> bf16 ------------------
__global__ void embnorm_k(const float* __restrict__ emb, unsigned short* __restrict__ embn,
                          float* __restrict__ rinv) {
  int row = blockIdx.x;
  int t = threadIdx.x;
  float4 v = ((const float4*)(emb + (size_t)row * D_N))[t];
  float ss = v.x * v.x + v.y * v.y + v.z * v.z + v.w * v.w;
  ss = wave_sum(ss);
  __shared__ float red[2];
  if ((t & 63) == 0) red[t >> 6] = ss;
  __syncthreads();
  float tot = red[0] + red[1];
  float ri = rsqrtf(tot);
  if (t == 0) rinv[row] = ri;
  ushort4 o;
  o.x = f2bf(v.x * ri); o.y = f2bf(v.y * ri); o.z = f2bf(v.z * ri); o.w = f2bf(v.w * ri);
  ((ushort4*)(embn + (size_t)row * D_N))[t] = o;
}

// ---------------- kernel 3: target logit (computes own label-col norm) -------
__global__ void target2_k(const float* __restrict__ emb, const float* __restrict__ Kp,
                          const float* __restrict__ rinv, const int* __restrict__ labels,
                          float* __restrict__ target, float* __restrict__ ctm,
                          float* __restrict__ ft) {
  int row = blockIdx.x;
  int t = threadIdx.x;
  int lab = labels[row];
  float p = 0.f, ss = 0.f;
  for (int d = t; d < D_N; d += 256) {
    float kv = Kp[(size_t)d * C_N + lab];
    p = fmaf(emb[(size_t)row * D_N + d], kv, p);
    ss = fmaf(kv, kv, ss);
  }
  p = wave_sum(p);
  ss = wave_sum(ss);
  __shared__ float redp[4], reds[4];
  if ((t & 63) == 0) { redp[t >> 6] = p; reds[t >> 6] = ss; }
  __syncthreads();
  if (t == 0) {
    float dot = redp[0] + redp[1] + redp[2] + redp[3];
    float sums = reds[0] + reds[1] + reds[2] + reds[3];
    float tg = dot * rinv[row] * rsqrtf(fmaxf(sums, 1e-30f));
    tg = fminf(fmaxf(tg, -1.f), 1.f);
    float st = sqrtf(fmaxf(1.f - tg * tg, 0.f));
    float cm = tg * COS_M_F - st * SIN_M_F;
    float f = (tg > THRESH_F) ? cm : (tg - MM_F);
    target[row] = tg;
    ctm[row] = cm;
    ft[row] = f;
  }
}

// ---------------- kernel 4: new_t reduction ----------------------------------
__global__ void newt_k(const float* __restrict__ target, const float* __restrict__ t_in,
                       float* __restrict__ newt) {
  int t = threadIdx.x;
  float v = target[t];
  v = wave_sum(v);
  __shared__ float red[8];
  if ((t & 63) == 0) red[t >> 6] = v;
  __syncthreads();
  if (t == 0) {
    float s = 0.f;
#pragma unroll
    for (int i = 0; i < 8; ++i) s += red[i];
    *newt = 0.01f * (s / (float)B_N) + 0.99f * t_in[0];
  }
}

// ---------------- kernel G10: BM=256 x BN=64, 256 thr, 4 indep blocks/CU -----
// m97-shaped concurrency: small independent barrier groups fill each other's
// stalls. Per-wave code identical to gemm2 (verified swizzles, dbuf 2-barrier
// loop). LDS exactly 40960 B (A 2x16K, B 2x4K) -> 4 blocks/CU. Params from
// global in epilogue. M-split=2 (sibling blocks share Knt j-tile).
__launch_bounds__(256, 4)
__global__ void gemm10_k(const unsigned short* __restrict__ Knt,
                         const unsigned short* __restrict__ embn,
                         const int* __restrict__ labels,
                         const float* __restrict__ ctm, const float* __restrict__ ft,
                         const float* __restrict__ newt_p, float* __restrict__ out) {
  __shared__ __align__(16) unsigned short Al[2][8192];  // 2 x 16384 B
  __shared__ __align__(16) unsigned short Bb[2][2048];  // 2 x 4096 B

  const int t = threadIdx.x;
  const int l = t & 63, w = t >> 6;          // 4 waves
  const int mi = blockIdx.x & 1;
  const int jb = blockIdx.x >> 1;
  const int m0 = mi * 256;
  const int j0 = jb * 64;

  // staging decode (verified): dest chunk l <-> source (r0, kc8)
  const int sidx = (l & 7) ^ (l >> 3);
  const int r0 = ((l >> 3) << 1) | (sidx >> 2);
  const int kc8 = (sidx & 3) * 8;

  const unsigned short* asrc = embn + (size_t)(m0 + w * 64 + r0) * D_N + kc8;
  const unsigned short* bsrc = Knt + (size_t)(j0 + w * 16 + r0) * D_N + kc8;

  // prologue: stage it=0 into buffer 0
#pragma unroll
  for (int p = 0; p < 4; ++p)
    lds_load16(asrc + p * 16 * D_N, &Al[0][w * 2048 + p * 512]);
  lds_load16(bsrc, &Bb[0][w * 512]);
  __syncthreads();

  const int wr = w >> 1, wc = w & 1;         // 2M x 2N waves; wave tile 128x32
  const int lq = l >> 4, lr = l & 15;
  const int s16 = ((((lr & 1) << 2) | lq) ^ (lr >> 1)) << 4;
  const int rh = lr >> 1;

  f32x4 acc[8][2];
#pragma unroll
  for (int mb = 0; mb < 8; ++mb) {
    acc[mb][0] = 0;
    acc[mb][1] = 0;
  }

#pragma unroll
  for (int it = 0; it < 16; ++it) {
    const int cur = it & 1, nxt = cur ^ 1;
    if (it < 15) {
      const int k0 = (it + 1) * 32;
#pragma unroll
      for (int p = 0; p < 4; ++p)
        lds_load16(asrc + p * 16 * D_N + k0, &Al[nxt][w * 2048 + p * 512]);
      lds_load16(bsrc + k0, &Bb[nxt][w * 512]);
    }
    const char* Ab = (const char*)Al[cur];
    const char* Bt = (const char*)Bb[cur];
    short8 b0 = *(const short8*)(Bt + ((wc * 16 + 0 + rh) << 7) + s16);
    short8 b1 = *(const short8*)(Bt + ((wc * 16 + 8 + rh) << 7) + s16);
#pragma unroll
    for (int mb = 0; mb < 8; ++mb) {
      short8 a = *(const short8*)(Ab + ((wr * 64 + mb * 8 + rh) << 7) + s16);
      acc[mb][0] = __builtin_amdgcn_mfma_f32_16x16x32_bf16(a, b0, acc[mb][0], 0, 0, 0);
      acc[mb][1] = __builtin_amdgcn_mfma_f32_16x16x32_bf16(a, b1, acc[mb][1], 0, 0, 0);
    }
    __syncthreads();
  }

  // ---- epilogue: gemm2-style guarded stores; params from global (L2-hot) ----
  const float newt = *newt_p;
  const int jn0 = j0 + wc * 32 + lr;
  const int jn1 = jn0 + 16;
#pragma unroll
  for (int mb = 0; mb < 8; ++mb) {
    const int ibase = wr * 128 + mb * 16 + 4 * lq;
#pragma unroll
    for (int r = 0; r < 4; ++r) {
      const int grow = m0 + ibase + r;
      const int lab = labels[grow];
      const float cm = ctm[grow];
      const float f = ft[grow];
      {
        float c = fminf(fmaxf(acc[mb][0][r], -1.f), 1.f);
        float o = (c > cm) ? c * (newt + c) : c;
        o = (jn0 == lab) ? f : o;
        if (jn0 < C_N) out[(size_t)grow * C_N + jn0] = o * S_F;
      }
      {
        float c = fminf(fmaxf(acc[mb][1][r], -1.f), 1.f);
        float o = (c > cm) ? c * (newt + c) : c;
        o = (jn1 == lab) ? f : o;
        if (jn1 < C_N) out[(size_t)grow * C_N + jn1] = o * S_F;
      }
    }
  }
}

// ---------------- launch -----------------------------------------------------
extern "C" void kernel_launch(void* const* d_in, const int* in_sizes, int n_in,
                              void* d_out, int out_size, void* d_ws, size_t ws_size,
                              hipStream_t stream) {
  (void)in_sizes; (void)n_in; (void)out_size; (void)ws_size;
  const float* emb = (const float*)d_in[0];
  const int* labels = (const int*)d_in[1];
  const float* Kp = (const float*)d_in[2];
  const float* t_in = (const float*)d_in[3];
  float* out = (float*)d_out;

  char* wsp = (char*)d_ws;
  const size_t KNT_BYTES = (size_t)100096 * D_N * 2;
  unsigned short* Knt = (unsigned short*)(wsp + 0);
  unsigned short* embn = (unsigned short*)(wsp + KNT_BYTES);
  float* cninv  = (float*)(wsp + KNT_BYTES + 524288);
  float* target = (float*)(wsp + KNT_BYTES + 524288 + 400000);
  float* ctm    = (float*)(wsp + KNT_BYTES + 524288 + 400000 + 2048);
  float* ft     = (float*)(wsp + KNT_BYTES + 524288 + 400000 + 2 * 2048);
  float* rinv   = (float*)(wsp + KNT_BYTES + 524288 + 400000 + 3 * 2048);
  float* newt   = (float*)(wsp + KNT_BYTES + 524288 + 400000 + 4 * 2048);

  knorm2_k<<<(C_N + 63) / 64, 512, 0, stream>>>(Kp, cninv, Knt);
  embnorm_k<<<B_N, 128, 0, stream>>>(emb, embn, rinv);
  target2_k<<<B_N, 256, 0, stream>>>(emb, Kp, rinv, labels, target, ctm, ft);
  newt_k<<<1, 512, 0, stream>>>(target, t_in, newt);
  const int jblocks = (C_N + 63) / 64;  // 1563
  gemm10_k<<<jblocks * 2, 256, 0, stream>>>(Knt, embn, labels, ctm, ft, newt, out);
}